// Round 14
// baseline (441.817 us; speedup 1.0000x reference)
//
#include <hip/hip_runtime.h>
#include <hip/hip_bf16.h>

#define NN 50000
#define NE 800000
#define NG 64
#define HID 64
#define NEG 0.2f
#define NBUCK 392       // dst>>7 buckets (128 dsts each)
#define CHUNK 2048      // edges per k_bucket block
#define KC_CAP 3072     // per-bucket ebuf segment (mean 2048 + ~22 sigma)
#define ROWP 66         // padded LDS row stride (floats)

// bf16 <-> f32 helpers (RNE pack, exact unpack)
__device__ __forceinline__ unsigned short f2bf(float f) {
    unsigned int u = __float_as_uint(f);
    unsigned int r = (u + 0x7FFF + ((u >> 16) & 1)) >> 16;
    return (unsigned short)r;
}
__device__ __forceinline__ float bf_lo(unsigned int p) { return __uint_as_float(p << 16); }
__device__ __forceinline__ float bf_hi(unsigned int p) { return __uint_as_float(p & 0xFFFF0000u); }
__device__ __forceinline__ float bf2f(unsigned short b) { return __uint_as_float(((unsigned int)b) << 16); }

// ---------------- K1: h(bf16) = x @ W ; a_s ; a_d --------------------------
// Register-tiled f32 GEMM. Block 0 zeroes gcur + pooled + cnt.
__global__ __launch_bounds__(256)
void k_xw(const float* __restrict__ x, const float* __restrict__ W,
          const float* __restrict__ att_s, const float* __restrict__ att_d,
          unsigned short* __restrict__ hb, float* __restrict__ as_, float* __restrict__ ad_,
          int* __restrict__ gcur, float* __restrict__ poolz) {
    __shared__ __align__(16) float sW[64][64];    // [k][c]
    __shared__ __align__(16) float sxT[64][68];   // [k][r]
    int t = threadIdx.x;
    if (blockIdx.x == 0) {
        for (int i = t; i < NBUCK; i += 256) gcur[i] = 0;
        for (int i = t; i < NG * HID + NG; i += 256) poolz[i] = 0.f;
    }
    int r0 = blockIdx.x * 64;
    for (int i = t; i < 4096; i += 256) sW[i >> 6][i & 63] = W[i];
    for (int i = t; i < 4096; i += 256) {
        int r = i >> 6, c = i & 63;
        int gr = r0 + r; if (gr >= NN) gr = NN - 1;
        sxT[c][r] = x[(size_t)gr * 64 + c];
    }
    __syncthreads();

    int tx = t & 15, ty = t >> 4;
    float4 asv = ((const float4*)att_s)[tx];
    float4 adv = ((const float4*)att_d)[tx];

    float acc[4][4] = {};
    #pragma unroll
    for (int k = 0; k < 64; ++k) {
        float4 a = *(const float4*)&sxT[k][4 * ty];
        float4 b = *(const float4*)&sW[k][4 * tx];
        float av[4] = {a.x, a.y, a.z, a.w};
        float bv[4] = {b.x, b.y, b.z, b.w};
        #pragma unroll
        for (int i = 0; i < 4; ++i)
            #pragma unroll
            for (int j = 0; j < 4; ++j)
                acc[i][j] += av[i] * bv[j];
    }

    #pragma unroll
    for (int i = 0; i < 4; ++i) {
        int r = r0 + 4 * ty + i;
        if (r < NN) {
            ushort4 hv;
            hv.x = f2bf(acc[i][0]); hv.y = f2bf(acc[i][1]);
            hv.z = f2bf(acc[i][2]); hv.w = f2bf(acc[i][3]);
            *(ushort4*)&hb[(size_t)r * 64 + 4 * tx] = hv;
            float ps = acc[i][0]*asv.x + acc[i][1]*asv.y + acc[i][2]*asv.z + acc[i][3]*asv.w;
            float pd = acc[i][0]*adv.x + acc[i][1]*adv.y + acc[i][2]*adv.z + acc[i][3]*adv.w;
            #pragma unroll
            for (int m = 1; m <= 8; m <<= 1) {
                ps += __shfl_xor(ps, m, 64);
                pd += __shfl_xor(pd, m, 64);
            }
            if (tx == 0) { as_[r] = ps; ad_[r] = pd; }
        }
    }
}

// ---------------- Pass B: bucket sort (dst>>7) + edge-weight precompute ---
// 512 threads; 392 bins. ebuf entry: int2{src<<7 | dst&127, ex_bits}.
__global__ __launch_bounds__(512)
void k_bucket(const int* __restrict__ src, const int* __restrict__ dst,
              const float* __restrict__ as_, const float* __restrict__ ad_,
              int* __restrict__ gcur, int2* __restrict__ ebuf) {
    __shared__ int lhist[512], lscan[512], loff[512], lcur[512], gbase[512];
    __shared__ int2 lsort[CHUNK];
    __shared__ unsigned short lbuck[CHUNK];
    int t = threadIdx.x;
    int base = blockIdx.x * CHUNK;
    int cnt = NE - base; if (cnt > CHUNK) cnt = CHUNK; if (cnt < 0) cnt = 0;

    int ds[4], ss[4];
    float ex[4];
    int nv = 0;
    #pragma unroll
    for (int j = 0; j < 4; ++j) {
        int e = base + j * 512 + t;
        if (e < NE) { ds[nv] = dst[e]; ss[nv] = src[e]; ++nv; }
    }
    for (int j = 0; j < nv; ++j) {            // independent gathers pipeline
        float e = as_[ss[j]] + ad_[ds[j]];
        e = e >= 0.f ? e : NEG * e;
        ex[j] = __expf(e);
    }
    lhist[t] = 0;
    __syncthreads();
    for (int j = 0; j < nv; ++j) atomicAdd(&lhist[ds[j] >> 7], 1);
    __syncthreads();
    lscan[t] = lhist[t];
    __syncthreads();
    for (int off = 1; off < 512; off <<= 1) {
        int u = (t >= off) ? lscan[t - off] : 0;
        __syncthreads();
        lscan[t] += u;
        __syncthreads();
    }
    loff[t] = lscan[t] - lhist[t];   // exclusive
    lcur[t] = 0;
    __syncthreads();
    for (int j = 0; j < nv; ++j) {
        int b = ds[j] >> 7;
        int r = atomicAdd(&lcur[b], 1);
        int slot = loff[b] + r;
        lsort[slot] = make_int2((ss[j] << 7) | (ds[j] & 127), __float_as_int(ex[j]));
        lbuck[slot] = (unsigned short)b;
    }
    if (t < NBUCK) {
        int c = lhist[t];
        gbase[t] = c ? atomicAdd(&gcur[t], c) : 0;    // offset WITHIN bucket t
    }
    __syncthreads();
    for (int i = t; i < cnt; i += 512) {
        int b = lbuck[i];
        ebuf[b * KC_CAP + gbase[b] + (i - loff[b])] = lsort[i];
    }
}

// ---------------- K-merged: per-bucket LDS accumulate + epilogue + pool ---
// Block = 1 bucket (128 dsts). Edge loop: 8 groups x 8 lanes per wave,
// atomicAdd bf16-h-slice * ex into padded LDS acc. Epilogue: self-loop,
// normalize + bias + relu in registers, run-length flush into pooled.
__global__ __launch_bounds__(256)
void k_merged(const int* __restrict__ gcur, const int2* __restrict__ ebuf,
              const unsigned short* __restrict__ hb,
              const float* __restrict__ as_, const float* __restrict__ ad_,
              const float* __restrict__ bias, const int* __restrict__ batch,
              float* __restrict__ pooled, float* __restrict__ cnt) {
    __shared__ float lacc[128 * ROWP];   // 33.8 KB
    __shared__ float lden[128];
    int t = threadIdx.x;
    int wave = t >> 6, lane = t & 63;
    int grp = lane >> 3, cc = lane & 7;
    int b = blockIdx.x;

    for (int i = t; i < 128 * ROWP; i += 256) lacc[i] = 0.f;
    if (t < 128) lden[t] = 0.f;
    __syncthreads();

    int sz = gcur[b];
    const int2* seg = ebuf + b * KC_CAP;

    for (int i0 = wave * 8; i0 < sz; i0 += 32) {
        int e = i0 + grp;
        if (e < sz) {
            int2 w = seg[e];                          // 8 lanes broadcast
            int   s  = w.x >> 7;
            int   dl = w.x & 127;
            float ex = __int_as_float(w.y);
            uint4 v = *(const uint4*)&hb[(size_t)s * 64 + 8 * cc];   // 16B/lane
            float* a = &lacc[dl * ROWP + 8 * cc];
            atomicAdd(a + 0, bf_lo(v.x) * ex);
            atomicAdd(a + 1, bf_hi(v.x) * ex);
            atomicAdd(a + 2, bf_lo(v.y) * ex);
            atomicAdd(a + 3, bf_hi(v.y) * ex);
            atomicAdd(a + 4, bf_lo(v.z) * ex);
            atomicAdd(a + 5, bf_hi(v.z) * ex);
            atomicAdd(a + 6, bf_lo(v.w) * ex);
            atomicAdd(a + 7, bf_hi(v.w) * ex);
            if (cc == 0) atomicAdd(&lden[dl], ex);
        }
    }
    __syncthreads();

    // epilogue: each wave owns 32 dst rows; channel = lane
    float bl = bias[lane];
    int dbase = b * 128 + wave * 32;
    float racc = 0.f, rcnt = 0.f;
    int cur = -1;
    for (int k = 0; k < 32; ++k) {
        int d = dbase + k;
        if (d >= NN) break;
        int gr = batch[d];                            // wave-uniform scalar
        if (gr != cur) {
            if (cur >= 0) {
                atomicAdd(&pooled[cur * 64 + lane], racc);
                if (lane == 0) atomicAdd(&cnt[cur], rcnt);
            }
            racc = 0.f; rcnt = 0.f; cur = gr;
        }
        float e0 = as_[d] + ad_[d];
        e0 = e0 >= 0.f ? e0 : NEG * e0;
        float ex0 = __expf(e0);
        int r = wave * 32 + k;
        float hs = bf2f(hb[(size_t)d * 64 + lane]);   // 2B/lane, 128B row
        float num = lacc[r * ROWP + lane] + ex0 * hs; // conflict-free read
        float den = lden[r] + ex0;
        float val = fmaxf(num / den + bl, 0.f);
        racc += val; rcnt += 1.f;
    }
    if (cur >= 0) {
        atomicAdd(&pooled[cur * 64 + lane], racc);
        if (lane == 0) atomicAdd(&cnt[cur], rcnt);
    }
}

// ---------------- K4: mean + MLP + sigmoid (single block) ------------------
__global__ __launch_bounds__(256)
void k_final(const float* __restrict__ pooled, const float* __restrict__ cnt,
             const float* __restrict__ w1, const float* __restrict__ b1,
             const float* __restrict__ w2, const float* __restrict__ b2,
             float* __restrict__ out) {
    __shared__ float sp[64][65];
    __shared__ float sz[64][65];
    int t = threadIdx.x;
    for (int i = t; i < 4096; i += 256) {
        int g = i >> 6, c = i & 63;
        sp[g][c] = pooled[i] / fmaxf(cnt[g], 1.0f);
    }
    __syncthreads();
    for (int i = t; i < 4096; i += 256) {
        int g = i >> 6, c = i & 63;
        float acc = b1[c];
        #pragma unroll
        for (int k = 0; k < 64; ++k) acc += sp[g][k] * w1[k * 64 + c];
        sz[g][c] = fmaxf(acc, 0.f);
    }
    __syncthreads();
    if (t < 64) {
        float acc = b2[0];
        #pragma unroll
        for (int c = 0; c < 64; ++c) acc += sz[t][c] * w2[c];
        out[t] = 1.f / (1.f + __expf(-acc));
    }
}

extern "C" void kernel_launch(void* const* d_in, const int* in_sizes, int n_in,
                              void* d_out, int out_size, void* d_ws, size_t ws_size,
                              hipStream_t stream) {
    const float* x     = (const float*)d_in[0];
    const int*   ei    = (const int*)d_in[1];   // [2, NE] flat: src row then dst row
    const int*   batch = (const int*)d_in[2];
    const float* W     = (const float*)d_in[3];
    const float* att_s = (const float*)d_in[4];
    const float* att_d = (const float*)d_in[5];
    const float* bias  = (const float*)d_in[6];
    const float* w1    = (const float*)d_in[7];
    const float* b1    = (const float*)d_in[8];
    const float* w2    = (const float*)d_in[9];
    const float* b2    = (const float*)d_in[10];
    float* out = (float*)d_out;

    const int* src = ei;
    const int* dst = ei + NE;

    // workspace layout
    unsigned short* hb = (unsigned short*)d_ws;      // NN*64 bf16 (6.4 MB)
    float* as_    = (float*)(hb + (size_t)NN * HID); // NN
    float* ad_    = as_ + NN;                        // NN
    float* pooled = ad_ + NN;                        // NG*64
    float* cntp   = pooled + NG * HID;               // NG
    int*   gcur   = (int*)(cntp + NG);               // NBUCK
    int2*  ebuf   = (int2*)(gcur + NBUCK);           // NBUCK*KC_CAP int2 (9.6 MB)

    k_xw<<<(NN + 63) / 64, 256, 0, stream>>>(x, W, att_s, att_d, hb, as_, ad_, gcur, pooled);

    k_bucket<<<(NE + CHUNK - 1) / CHUNK, 512, 0, stream>>>(src, dst, as_, ad_, gcur, ebuf);

    k_merged<<<NBUCK, 256, 0, stream>>>(gcur, ebuf, hb, as_, ad_, bias, batch, pooled, cntp);

    k_final<<<1, 256, 0, stream>>>(pooled, cntp, w1, b1, w2, b2, out);
}

// Round 15
// 210.740 us; speedup vs baseline: 2.0965x; 2.0965x over previous
//
#include <hip/hip_runtime.h>
#include <hip/hip_bf16.h>

#define NN 50000
#define NE 800000
#define NG 64
#define HID 64
#define NEG 0.2f
#define NPW 64          // nodes per wave in k_node
#define NBUCK 196       // ceil(NN/256) coarse buckets (dst>>8)
#define CHUNK 2048      // edges per k_bucket block
#define KC_CAP 6144     // per-bucket ebuf segment (mean 4081 + 32 sigma)

// ---- fp8 e4m3 software encode (RNE) / decode ------------------------------
__device__ __forceinline__ unsigned int f2fp8(float f) {
    unsigned int u = __float_as_uint(f);
    unsigned int sign = (u >> 24) & 0x80;
    unsigned int au = u & 0x7FFFFFFF;
    if (au >= 0x43E00000u) return sign | 0x7E;            // clamp to +-448
    if (au < 0x3C800000u) {                               // denormal: step 2^-9
        int m = (int)rintf(__uint_as_float(au) * 512.f);  // 0..8 (8 -> 2^-6 exactly)
        return sign | (unsigned int)m;
    }
    unsigned int r = au + 0x7FFFF + ((au >> 20) & 1);     // RNE to 3-bit mantissa
    unsigned int e = (r >> 23) - 120;                     // 127-7
    unsigned int m = (r >> 20) & 7;
    return sign | (e << 3) | m;
}
__device__ __forceinline__ float fp8dec(int i) {
    int e = (i >> 3) & 15, m = i & 7;
    float v = e ? ldexpf((float)(8 + m), e - 10) : ldexpf((float)m, -9);
    return (i & 0x80) ? -v : v;
}

// ---------------- K1: h(fp8) = x @ W ; a_s ; a_d ---------------------------
__global__ __launch_bounds__(256)
void k_xw(const float* __restrict__ x, const float* __restrict__ W,
          const float* __restrict__ att_s, const float* __restrict__ att_d,
          unsigned char* __restrict__ h8, float* __restrict__ as_, float* __restrict__ ad_,
          int* __restrict__ gcur) {
    __shared__ __align__(16) float sW[64][64];    // [k][c]
    __shared__ __align__(16) float sxT[64][68];   // [k][r]
    int t = threadIdx.x;
    if (blockIdx.x == 0 && t < NBUCK) gcur[t] = 0;
    int r0 = blockIdx.x * 64;
    for (int i = t; i < 4096; i += 256) sW[i >> 6][i & 63] = W[i];
    for (int i = t; i < 4096; i += 256) {
        int r = i >> 6, c = i & 63;
        int gr = r0 + r; if (gr >= NN) gr = NN - 1;
        sxT[c][r] = x[(size_t)gr * 64 + c];
    }
    __syncthreads();

    int tx = t & 15, ty = t >> 4;
    float4 asv = ((const float4*)att_s)[tx];
    float4 adv = ((const float4*)att_d)[tx];

    float acc[4][4] = {};
    #pragma unroll
    for (int k = 0; k < 64; ++k) {
        float4 a = *(const float4*)&sxT[k][4 * ty];
        float4 b = *(const float4*)&sW[k][4 * tx];
        float av[4] = {a.x, a.y, a.z, a.w};
        float bv[4] = {b.x, b.y, b.z, b.w};
        #pragma unroll
        for (int i = 0; i < 4; ++i)
            #pragma unroll
            for (int j = 0; j < 4; ++j)
                acc[i][j] += av[i] * bv[j];
    }

    #pragma unroll
    for (int i = 0; i < 4; ++i) {
        int r = r0 + 4 * ty + i;
        if (r < NN) {
            unsigned int p = f2fp8(acc[i][0]) | (f2fp8(acc[i][1]) << 8)
                           | (f2fp8(acc[i][2]) << 16) | (f2fp8(acc[i][3]) << 24);
            *(unsigned int*)&h8[(size_t)r * 64 + 4 * tx] = p;   // 4B store
            float ps = acc[i][0]*asv.x + acc[i][1]*asv.y + acc[i][2]*asv.z + acc[i][3]*asv.w;
            float pd = acc[i][0]*adv.x + acc[i][1]*adv.y + acc[i][2]*adv.z + acc[i][3]*adv.w;
            #pragma unroll
            for (int m = 1; m <= 8; m <<= 1) {
                ps += __shfl_xor(ps, m, 64);
                pd += __shfl_xor(pd, m, 64);
            }
            if (tx == 0) { as_[r] = ps; ad_[r] = pd; }
        }
    }
}

// ---------------- Pass B: bucket sort + edge-weight precompute ------------
// ex = exp(lrelu(as[src]+ad[dst])) computed here (src+dst both in regs).
__global__ __launch_bounds__(256)
void k_bucket(const int* __restrict__ src, const int* __restrict__ dst,
              const float* __restrict__ as_, const float* __restrict__ ad_,
              int* __restrict__ gcur, int2* __restrict__ ebuf) {
    __shared__ int lhist[256], lscan[256], loff[256], lcur[256], gbase[256];
    __shared__ int2 lsort[CHUNK];
    __shared__ unsigned char lbuck[CHUNK];
    int t = threadIdx.x;
    int base = blockIdx.x * CHUNK;
    int cnt = NE - base; if (cnt > CHUNK) cnt = CHUNK; if (cnt < 0) cnt = 0;

    int ds[8], ss[8];
    float ex[8];
    int nv = 0;
    #pragma unroll
    for (int j = 0; j < 8; ++j) {
        int e = base + j * 256 + t;
        if (e < NE) { ds[nv] = dst[e]; ss[nv] = src[e]; ++nv; }
    }
    for (int j = 0; j < nv; ++j) {
        float e = as_[ss[j]] + ad_[ds[j]];
        e = e >= 0.f ? e : NEG * e;
        ex[j] = __expf(e);
    }
    lhist[t] = 0;
    __syncthreads();
    for (int j = 0; j < nv; ++j) atomicAdd(&lhist[ds[j] >> 8], 1);
    __syncthreads();
    lscan[t] = lhist[t];
    __syncthreads();
    for (int off = 1; off < 256; off <<= 1) {
        int u = (t >= off) ? lscan[t - off] : 0;
        __syncthreads();
        lscan[t] += u;
        __syncthreads();
    }
    loff[t] = lscan[t] - lhist[t];   // exclusive
    lcur[t] = 0;
    __syncthreads();
    for (int j = 0; j < nv; ++j) {
        int b = ds[j] >> 8;
        int r = atomicAdd(&lcur[b], 1);
        int slot = loff[b] + r;
        lsort[slot] = make_int2((ss[j] << 8) | (ds[j] & 255), __float_as_int(ex[j]));
        lbuck[slot] = (unsigned char)b;
    }
    if (t < NBUCK) {
        int c = lhist[t];
        gbase[t] = c ? atomicAdd(&gcur[t], c) : 0;    // offset WITHIN bucket t
    }
    __syncthreads();
    for (int i = t; i < cnt; i += 256) {
        int b = lbuck[i];
        ebuf[b * KC_CAP + gbase[b] + (i - loff[b])] = lsort[i];
    }
}

// ---------------- Pass C: exact CSR within each bucket --------------------
__global__ __launch_bounds__(256)
void k_csr(const int* __restrict__ gcur, const int2* __restrict__ ebuf,
           int2* __restrict__ csr2, int* __restrict__ cursor, int* __restrict__ deg) {
    __shared__ int lhist[256], lscan[256], loff[256], lcur[256], bscan[256];
    __shared__ int2 lsrc[KC_CAP];
    int t = threadIdx.x;
    int b = blockIdx.x;

    bscan[t] = (t < NBUCK) ? gcur[t] : 0;
    __syncthreads();
    for (int off = 1; off < 256; off <<= 1) {
        int u = (t >= off) ? bscan[t - off] : 0;
        __syncthreads();
        bscan[t] += u;
        __syncthreads();
    }
    int sz = gcur[b];
    int gb = bscan[b] - sz;
    const int2* seg = ebuf + b * KC_CAP;

    lhist[t] = 0;
    __syncthreads();
    for (int i = t; i < sz; i += 256)
        atomicAdd(&lhist[seg[i].x & 255], 1);
    __syncthreads();
    lscan[t] = lhist[t];
    __syncthreads();
    for (int off = 1; off < 256; off <<= 1) {
        int u = (t >= off) ? lscan[t - off] : 0;
        __syncthreads();
        lscan[t] += u;
        __syncthreads();
    }
    loff[t] = lscan[t] - lhist[t];
    lcur[t] = 0;
    __syncthreads();
    for (int i = t; i < sz; i += 256) {
        int2 w = seg[i];
        int dl = w.x & 255;
        int r = atomicAdd(&lcur[dl], 1);
        lsrc[loff[dl] + r] = make_int2(w.x >> 8, w.y);
    }
    __syncthreads();
    for (int i = t; i < sz; i += 256)
        csr2[gb + i] = lsrc[i];
    int d = b * 256 + t;
    if (d < NN) {
        deg[d] = lhist[t];
        cursor[d] = gb + loff[t] + lhist[t];   // end offset
    }
}

// ---------------- K2': gather, 8 edges/iter, fp8 h + LDS LUT decode -------
__global__ __launch_bounds__(256)
void k_gather(const int2* __restrict__ csr2, const int* __restrict__ cursor,
              const int* __restrict__ deg, const unsigned char* __restrict__ h8,
              const float* __restrict__ as_, const float* __restrict__ ad_,
              const float* __restrict__ bias, float* __restrict__ g,
              float* __restrict__ poolz) {
    __shared__ float lut[256];
    int t = threadIdx.x;
    if (t < 256) lut[t] = fp8dec(t);
    if (blockIdx.x == 0) {
        for (int i = t; i < NG * HID + NG; i += 256) poolz[i] = 0.f;
    }
    __syncthreads();
    int wave = t >> 6, lane = t & 63;
    int d = blockIdx.x * 4 + wave;          // grid exactly covers NN (12500*4)
    if (d >= NN) return;
    int grp = lane >> 3;          // edge group 0..7
    int cc  = lane & 7;           // channel slice (8 channels each)
    int cend = cursor[d];
    int nd   = deg[d];
    int cbeg = cend - nd;

    float acc[8] = {};
    float den = 0.f;

    // self-loop (weight nonzero only in group 0; summed once by the reduce)
    {
        float e0 = as_[d] + ad_[d];
        e0 = e0 >= 0.f ? e0 : NEG * e0;
        float ex0 = (grp == 0) ? __expf(e0) : 0.f;
        den += ex0;
        uint2 v = *(const uint2*)&h8[(size_t)d * 64 + 8 * cc];
        acc[0] += lut[v.x & 255] * ex0;         acc[1] += lut[(v.x >> 8) & 255] * ex0;
        acc[2] += lut[(v.x >> 16) & 255] * ex0; acc[3] += lut[(v.x >> 24) & 255] * ex0;
        acc[4] += lut[v.y & 255] * ex0;         acc[5] += lut[(v.y >> 8) & 255] * ex0;
        acc[6] += lut[(v.y >> 16) & 255] * ex0; acc[7] += lut[(v.y >> 24) & 255] * ex0;
    }

    for (int c0 = 0; c0 < nd; c0 += 8) {
        int  e  = c0 + grp;
        bool ok = e < nd;
        int  ci = cbeg + (ok ? e : (nd - 1));
        int2 se = csr2[ci];                       // coalesced (s, ex)
        int    s  = se.x;
        float  ex = ok ? __int_as_float(se.y) : 0.f;
        den += ex;
        uint2 v = *(const uint2*)&h8[(size_t)s * 64 + 8 * cc];   // 8B/lane, 64B row
        acc[0] += lut[v.x & 255] * ex;         acc[1] += lut[(v.x >> 8) & 255] * ex;
        acc[2] += lut[(v.x >> 16) & 255] * ex; acc[3] += lut[(v.x >> 24) & 255] * ex;
        acc[4] += lut[v.y & 255] * ex;         acc[5] += lut[(v.y >> 8) & 255] * ex;
        acc[6] += lut[(v.y >> 16) & 255] * ex; acc[7] += lut[(v.y >> 24) & 255] * ex;
    }

    #pragma unroll
    for (int m = 8; m <= 32; m <<= 1) {
        den += __shfl_xor(den, m, 64);
        #pragma unroll
        for (int k = 0; k < 8; ++k) acc[k] += __shfl_xor(acc[k], m, 64);
    }

    if (grp == 0) {                               // 8 lanes write the row
        float inv = 1.f / den;
        float4 b0 = ((const float4*)bias)[2 * cc];
        float4 b1 = ((const float4*)bias)[2 * cc + 1];
        float4 o0, o1;
        o0.x = fmaxf(acc[0] * inv + b0.x, 0.f);
        o0.y = fmaxf(acc[1] * inv + b0.y, 0.f);
        o0.z = fmaxf(acc[2] * inv + b0.z, 0.f);
        o0.w = fmaxf(acc[3] * inv + b0.w, 0.f);
        o1.x = fmaxf(acc[4] * inv + b1.x, 0.f);
        o1.y = fmaxf(acc[5] * inv + b1.y, 0.f);
        o1.z = fmaxf(acc[6] * inv + b1.z, 0.f);
        o1.w = fmaxf(acc[7] * inv + b1.w, 0.f);
        *(float4*)&g[(size_t)d * 64 + 8 * cc]     = o0;
        *(float4*)&g[(size_t)d * 64 + 8 * cc + 4] = o1;
    }
}

// ---------------- K3: pooled partial sums (batch sorted, run-length) ------
__global__ __launch_bounds__(256)
void k_node(const float* __restrict__ g, const int* __restrict__ batch,
            float* __restrict__ pooled, float* __restrict__ cnt) {
    int t = threadIdx.x;
    int wave = t >> 6, lane = t & 63;
    int n0 = (blockIdx.x * 4 + wave) * NPW;
    if (n0 >= NN) return;
    int n1 = n0 + NPW; if (n1 > NN) n1 = NN;
    float acc = 0.f, c = 0.f;
    int cur = batch[n0];
    for (int n = n0; n < n1; ++n) {
        int gr = batch[n];
        if (gr != cur) {
            atomicAdd(&pooled[cur * 64 + lane], acc);
            if (lane == 0) atomicAdd(&cnt[cur], c);
            acc = 0.f; c = 0.f; cur = gr;
        }
        acc += g[(size_t)n * 64 + lane];
        c += 1.f;
    }
    atomicAdd(&pooled[cur * 64 + lane], acc);
    if (lane == 0) atomicAdd(&cnt[cur], c);
}

// ---------------- K4: mean + MLP + sigmoid (single block) ------------------
__global__ __launch_bounds__(256)
void k_final(const float* __restrict__ pooled, const float* __restrict__ cnt,
             const float* __restrict__ w1, const float* __restrict__ b1,
             const float* __restrict__ w2, const float* __restrict__ b2,
             float* __restrict__ out) {
    __shared__ float sp[64][65];
    __shared__ float sz[64][65];
    int t = threadIdx.x;
    for (int i = t; i < 4096; i += 256) {
        int g = i >> 6, c = i & 63;
        sp[g][c] = pooled[i] / fmaxf(cnt[g], 1.0f);
    }
    __syncthreads();
    for (int i = t; i < 4096; i += 256) {
        int g = i >> 6, c = i & 63;
        float acc = b1[c];
        #pragma unroll
        for (int k = 0; k < 64; ++k) acc += sp[g][k] * w1[k * 64 + c];
        sz[g][c] = fmaxf(acc, 0.f);
    }
    __syncthreads();
    if (t < 64) {
        float acc = b2[0];
        #pragma unroll
        for (int c = 0; c < 64; ++c) acc += sz[t][c] * w2[c];
        out[t] = 1.f / (1.f + __expf(-acc));
    }
}

extern "C" void kernel_launch(void* const* d_in, const int* in_sizes, int n_in,
                              void* d_out, int out_size, void* d_ws, size_t ws_size,
                              hipStream_t stream) {
    const float* x     = (const float*)d_in[0];
    const int*   ei    = (const int*)d_in[1];   // [2, NE] flat: src row then dst row
    const int*   batch = (const int*)d_in[2];
    const float* W     = (const float*)d_in[3];
    const float* att_s = (const float*)d_in[4];
    const float* att_d = (const float*)d_in[5];
    const float* bias  = (const float*)d_in[6];
    const float* w1    = (const float*)d_in[7];
    const float* b1    = (const float*)d_in[8];
    const float* w2    = (const float*)d_in[9];
    const float* b2    = (const float*)d_in[10];
    float* out = (float*)d_out;

    const int* src = ei;
    const int* dst = ei + NE;

    // workspace layout
    unsigned char* h8 = (unsigned char*)d_ws;        // NN*64 fp8 (3.2 MB)
    float* as_    = (float*)(h8 + (size_t)NN * HID); // NN
    float* ad_    = as_ + NN;                        // NN
    float* g      = ad_ + NN;                        // NN*64 f32 (12.8 MB, ebuf aliases)
    float* pooled = g + (size_t)NN * HID;            // NG*64
    float* cntp   = pooled + NG * HID;               // NG
    int*   deg    = (int*)(cntp + NG);               // NN
    int*   cursor = deg + NN;                        // NN
    int2*  csr2   = (int2*)(cursor + NN);            // NE int2 (6.4 MB)
    int*   gcur   = (int*)(csr2 + NE);               // NBUCK
    int2*  ebuf   = (int2*)g;                        // NBUCK*KC_CAP int2 (9.6 MB < 12.8)

    k_xw<<<(NN + 63) / 64, 256, 0, stream>>>(x, W, att_s, att_d, h8, as_, ad_, gcur);

    k_bucket<<<(NE + CHUNK - 1) / CHUNK, 256, 0, stream>>>(src, dst, as_, ad_, gcur, ebuf);
    k_csr<<<NBUCK, 256, 0, stream>>>(gcur, ebuf, csr2, cursor, deg);

    k_gather<<<(NN + 3) / 4, 256, 0, stream>>>(csr2, cursor, deg, h8, as_, ad_, bias, g, pooled);

    k_node<<<(NN / (4 * NPW)) + 1, 256, 0, stream>>>(g, batch, pooled, cntp);

    k_final<<<1, 256, 0, stream>>>(pooled, cntp, w1, b1, w2, b2, out);
}

// Round 17
// 155.991 us; speedup vs baseline: 2.8323x; 1.3510x over previous
//
#include <hip/hip_runtime.h>
#include <hip/hip_bf16.h>

#define NN 50000
#define NE 800000
#define NG 64
#define HID 64
#define NEG 0.2f
#define NPW 64          // nodes per wave in k_node
#define NBUCK 196       // ceil(NN/256) coarse buckets (dst>>8)
#define CHUNK 2048      // edges per k_bucket block
#define KC_CAP 6144     // per-bucket ebuf segment (mean 4081 + 32 sigma)

// ---- fp8 e4m3 BRANCH-FREE encode (RNE) / decode ---------------------------
// Magic-add denormal path: float_as_int(a*512 + 1.5*2^23) - 0x4B400000
// (bit pattern of 1.5*2^23, NOT its decimal value -- r16 bug).
__device__ __forceinline__ unsigned int f2fp8(float f) {
    unsigned int sign = (__float_as_uint(f) >> 24) & 0x80;
    float a = fminf(fabsf(f), 448.f);
    unsigned int au = __float_as_uint(a);
    // normal path: RNE to 3 mantissa bits
    unsigned int r = au + 0x7FFFF + ((au >> 20) & 1);
    unsigned int enc_n = (((r >> 23) - 120) << 3) | ((r >> 20) & 7);
    // denormal path (a < 2^-6): round a*512 to nearest int (0..8) via magic add
    float t = fmaf(a, 512.f, 12582912.f);               // 1.5*2^23
    unsigned int enc_d = (unsigned int)(__float_as_int(t) - 0x4B400000);  // FIX
    unsigned int enc = (au < 0x3C800000u) ? enc_d : enc_n;
    return sign | enc;
}
__device__ __forceinline__ float fp8dec(int i) {        // LUT init only
    int e = (i >> 3) & 15, m = i & 7;
    float v = e ? ldexpf((float)(8 + m), e - 10) : ldexpf((float)m, -9);
    return (i & 0x80) ? -v : v;
}

// ---------------- K1: h(fp8) = x @ W ; a_s ; a_d ---------------------------
__global__ __launch_bounds__(256)
void k_xw(const float* __restrict__ x, const float* __restrict__ W,
          const float* __restrict__ att_s, const float* __restrict__ att_d,
          unsigned char* __restrict__ h8, float* __restrict__ as_, float* __restrict__ ad_,
          int* __restrict__ gcur) {
    __shared__ __align__(16) float sW[64][64];    // [k][c]
    __shared__ __align__(16) float sxT[64][68];   // [k][r]
    int t = threadIdx.x;
    if (blockIdx.x == 0 && t < NBUCK) gcur[t] = 0;
    int r0 = blockIdx.x * 64;
    for (int i = t; i < 4096; i += 256) sW[i >> 6][i & 63] = W[i];
    for (int i = t; i < 4096; i += 256) {
        int r = i >> 6, c = i & 63;
        int gr = r0 + r; if (gr >= NN) gr = NN - 1;
        sxT[c][r] = x[(size_t)gr * 64 + c];
    }
    __syncthreads();

    int tx = t & 15, ty = t >> 4;
    float4 asv = ((const float4*)att_s)[tx];
    float4 adv = ((const float4*)att_d)[tx];

    float acc[4][4] = {};
    #pragma unroll
    for (int k = 0; k < 64; ++k) {
        float4 a = *(const float4*)&sxT[k][4 * ty];
        float4 b = *(const float4*)&sW[k][4 * tx];
        float av[4] = {a.x, a.y, a.z, a.w};
        float bv[4] = {b.x, b.y, b.z, b.w};
        #pragma unroll
        for (int i = 0; i < 4; ++i)
            #pragma unroll
            for (int j = 0; j < 4; ++j)
                acc[i][j] += av[i] * bv[j];
    }

    #pragma unroll
    for (int i = 0; i < 4; ++i) {
        int r = r0 + 4 * ty + i;
        if (r < NN) {
            unsigned int p = f2fp8(acc[i][0]) | (f2fp8(acc[i][1]) << 8)
                           | (f2fp8(acc[i][2]) << 16) | (f2fp8(acc[i][3]) << 24);
            *(unsigned int*)&h8[(size_t)r * 64 + 4 * tx] = p;   // 4B store
            float ps = acc[i][0]*asv.x + acc[i][1]*asv.y + acc[i][2]*asv.z + acc[i][3]*asv.w;
            float pd = acc[i][0]*adv.x + acc[i][1]*adv.y + acc[i][2]*adv.z + acc[i][3]*adv.w;
            #pragma unroll
            for (int m = 1; m <= 8; m <<= 1) {
                ps += __shfl_xor(ps, m, 64);
                pd += __shfl_xor(pd, m, 64);
            }
            if (tx == 0) { as_[r] = ps; ad_[r] = pd; }
        }
    }
}

// ---------------- Pass B: bucket sort + edge-weight precompute ------------
__global__ __launch_bounds__(256)
void k_bucket(const int* __restrict__ src, const int* __restrict__ dst,
              const float* __restrict__ as_, const float* __restrict__ ad_,
              int* __restrict__ gcur, int2* __restrict__ ebuf) {
    __shared__ int lhist[256], lscan[256], loff[256], lcur[256], gbase[256];
    __shared__ int2 lsort[CHUNK];
    __shared__ unsigned char lbuck[CHUNK];
    int t = threadIdx.x;
    int base = blockIdx.x * CHUNK;
    int cnt = NE - base; if (cnt > CHUNK) cnt = CHUNK; if (cnt < 0) cnt = 0;

    int ds[8], ss[8];
    float ex[8];
    int nv = 0;
    #pragma unroll
    for (int j = 0; j < 8; ++j) {
        int e = base + j * 256 + t;
        if (e < NE) { ds[nv] = dst[e]; ss[nv] = src[e]; ++nv; }
    }
    for (int j = 0; j < nv; ++j) {
        float e = as_[ss[j]] + ad_[ds[j]];
        e = e >= 0.f ? e : NEG * e;
        ex[j] = __expf(e);
    }
    lhist[t] = 0;
    __syncthreads();
    for (int j = 0; j < nv; ++j) atomicAdd(&lhist[ds[j] >> 8], 1);
    __syncthreads();
    lscan[t] = lhist[t];
    __syncthreads();
    for (int off = 1; off < 256; off <<= 1) {
        int u = (t >= off) ? lscan[t - off] : 0;
        __syncthreads();
        lscan[t] += u;
        __syncthreads();
    }
    loff[t] = lscan[t] - lhist[t];   // exclusive
    lcur[t] = 0;
    __syncthreads();
    for (int j = 0; j < nv; ++j) {
        int b = ds[j] >> 8;
        int r = atomicAdd(&lcur[b], 1);
        int slot = loff[b] + r;
        lsort[slot] = make_int2((ss[j] << 8) | (ds[j] & 255), __float_as_int(ex[j]));
        lbuck[slot] = (unsigned char)b;
    }
    if (t < NBUCK) {
        int c = lhist[t];
        gbase[t] = c ? atomicAdd(&gcur[t], c) : 0;    // offset WITHIN bucket t
    }
    __syncthreads();
    for (int i = t; i < cnt; i += 256) {
        int b = lbuck[i];
        ebuf[b * KC_CAP + gbase[b] + (i - loff[b])] = lsort[i];
    }
}

// ---------------- Pass C: exact CSR within each bucket --------------------
__global__ __launch_bounds__(256)
void k_csr(const int* __restrict__ gcur, const int2* __restrict__ ebuf,
           int2* __restrict__ csr2, int* __restrict__ cursor, int* __restrict__ deg) {
    __shared__ int lhist[256], lscan[256], loff[256], lcur[256], bscan[256];
    __shared__ int2 lsrc[KC_CAP];
    int t = threadIdx.x;
    int b = blockIdx.x;

    bscan[t] = (t < NBUCK) ? gcur[t] : 0;
    __syncthreads();
    for (int off = 1; off < 256; off <<= 1) {
        int u = (t >= off) ? bscan[t - off] : 0;
        __syncthreads();
        bscan[t] += u;
        __syncthreads();
    }
    int sz = gcur[b];
    int gb = bscan[b] - sz;
    const int2* seg = ebuf + b * KC_CAP;

    lhist[t] = 0;
    __syncthreads();
    for (int i = t; i < sz; i += 256)
        atomicAdd(&lhist[seg[i].x & 255], 1);
    __syncthreads();
    lscan[t] = lhist[t];
    __syncthreads();
    for (int off = 1; off < 256; off <<= 1) {
        int u = (t >= off) ? lscan[t - off] : 0;
        __syncthreads();
        lscan[t] += u;
        __syncthreads();
    }
    loff[t] = lscan[t] - lhist[t];
    lcur[t] = 0;
    __syncthreads();
    for (int i = t; i < sz; i += 256) {
        int2 w = seg[i];
        int dl = w.x & 255;
        int r = atomicAdd(&lcur[dl], 1);
        lsrc[loff[dl] + r] = make_int2(w.x >> 8, w.y);
    }
    __syncthreads();
    for (int i = t; i < sz; i += 256)
        csr2[gb + i] = lsrc[i];
    int d = b * 256 + t;
    if (d < NN) {
        deg[d] = lhist[t];
        cursor[d] = gb + loff[t] + lhist[t];   // end offset
    }
}

// ---------------- K2': gather, 8 edges/iter, fp8 h + LDS LUT decode -------
__global__ __launch_bounds__(256)
void k_gather(const int2* __restrict__ csr2, const int* __restrict__ cursor,
              const int* __restrict__ deg, const unsigned char* __restrict__ h8,
              const float* __restrict__ as_, const float* __restrict__ ad_,
              const float* __restrict__ bias, float* __restrict__ g,
              float* __restrict__ poolz) {
    __shared__ float lut[256];
    int t = threadIdx.x;
    if (t < 256) lut[t] = fp8dec(t);
    if (blockIdx.x == 0) {
        for (int i = t; i < NG * HID + NG; i += 256) poolz[i] = 0.f;
    }
    __syncthreads();
    int wave = t >> 6, lane = t & 63;
    int d = blockIdx.x * 4 + wave;
    if (d >= NN) return;
    int grp = lane >> 3;          // edge group 0..7
    int cc  = lane & 7;           // channel slice (8 channels each)
    int cend = cursor[d];
    int nd   = deg[d];
    int cbeg = cend - nd;

    float acc[8] = {};
    float den = 0.f;

    // self-loop (weight nonzero only in group 0; summed once by the reduce)
    {
        float e0 = as_[d] + ad_[d];
        e0 = e0 >= 0.f ? e0 : NEG * e0;
        float ex0 = (grp == 0) ? __expf(e0) : 0.f;
        den += ex0;
        uint2 v = *(const uint2*)&h8[(size_t)d * 64 + 8 * cc];
        acc[0] += lut[v.x & 255] * ex0;         acc[1] += lut[(v.x >> 8) & 255] * ex0;
        acc[2] += lut[(v.x >> 16) & 255] * ex0; acc[3] += lut[(v.x >> 24) & 255] * ex0;
        acc[4] += lut[v.y & 255] * ex0;         acc[5] += lut[(v.y >> 8) & 255] * ex0;
        acc[6] += lut[(v.y >> 16) & 255] * ex0; acc[7] += lut[(v.y >> 24) & 255] * ex0;
    }

    for (int c0 = 0; c0 < nd; c0 += 8) {
        int  e  = c0 + grp;
        bool ok = e < nd;
        int  ci = cbeg + (ok ? e : (nd - 1));
        int2 se = csr2[ci];                       // coalesced (s, ex)
        int    s  = se.x;
        float  ex = ok ? __int_as_float(se.y) : 0.f;
        den += ex;
        uint2 v = *(const uint2*)&h8[(size_t)s * 64 + 8 * cc];   // 8B/lane, 64B row
        acc[0] += lut[v.x & 255] * ex;         acc[1] += lut[(v.x >> 8) & 255] * ex;
        acc[2] += lut[(v.x >> 16) & 255] * ex; acc[3] += lut[(v.x >> 24) & 255] * ex;
        acc[4] += lut[v.y & 255] * ex;         acc[5] += lut[(v.y >> 8) & 255] * ex;
        acc[6] += lut[(v.y >> 16) & 255] * ex; acc[7] += lut[(v.y >> 24) & 255] * ex;
    }

    #pragma unroll
    for (int m = 8; m <= 32; m <<= 1) {
        den += __shfl_xor(den, m, 64);
        #pragma unroll
        for (int k = 0; k < 8; ++k) acc[k] += __shfl_xor(acc[k], m, 64);
    }

    if (grp == 0) {                               // 8 lanes write the row
        float inv = 1.f / den;
        float4 b0 = ((const float4*)bias)[2 * cc];
        float4 b1 = ((const float4*)bias)[2 * cc + 1];
        float4 o0, o1;
        o0.x = fmaxf(acc[0] * inv + b0.x, 0.f);
        o0.y = fmaxf(acc[1] * inv + b0.y, 0.f);
        o0.z = fmaxf(acc[2] * inv + b0.z, 0.f);
        o0.w = fmaxf(acc[3] * inv + b0.w, 0.f);
        o1.x = fmaxf(acc[4] * inv + b1.x, 0.f);
        o1.y = fmaxf(acc[5] * inv + b1.y, 0.f);
        o1.z = fmaxf(acc[6] * inv + b1.z, 0.f);
        o1.w = fmaxf(acc[7] * inv + b1.w, 0.f);
        *(float4*)&g[(size_t)d * 64 + 8 * cc]     = o0;
        *(float4*)&g[(size_t)d * 64 + 8 * cc + 4] = o1;
    }
}

// ---------------- K3: pooled partial sums (batch sorted, run-length) ------
__global__ __launch_bounds__(256)
void k_node(const float* __restrict__ g, const int* __restrict__ batch,
            float* __restrict__ pooled, float* __restrict__ cnt) {
    int t = threadIdx.x;
    int wave = t >> 6, lane = t & 63;
    int n0 = (blockIdx.x * 4 + wave) * NPW;
    if (n0 >= NN) return;
    int n1 = n0 + NPW; if (n1 > NN) n1 = NN;
    float acc = 0.f, c = 0.f;
    int cur = batch[n0];
    for (int n = n0; n < n1; ++n) {
        int gr = batch[n];
        if (gr != cur) {
            atomicAdd(&pooled[cur * 64 + lane], acc);
            if (lane == 0) atomicAdd(&cnt[cur], c);
            acc = 0.f; c = 0.f; cur = gr;
        }
        acc += g[(size_t)n * 64 + lane];
        c += 1.f;
    }
    atomicAdd(&pooled[cur * 64 + lane], acc);
    if (lane == 0) atomicAdd(&cnt[cur], c);
}

// ---------------- K4: mean + MLP + sigmoid (single block) ------------------
__global__ __launch_bounds__(256)
void k_final(const float* __restrict__ pooled, const float* __restrict__ cnt,
             const float* __restrict__ w1, const float* __restrict__ b1,
             const float* __restrict__ w2, const float* __restrict__ b2,
             float* __restrict__ out) {
    __shared__ float sp[64][65];
    __shared__ float sz[64][65];
    int t = threadIdx.x;
    for (int i = t; i < 4096; i += 256) {
        int g = i >> 6, c = i & 63;
        sp[g][c] = pooled[i] / fmaxf(cnt[g], 1.0f);
    }
    __syncthreads();
    for (int i = t; i < 4096; i += 256) {
        int g = i >> 6, c = i & 63;
        float acc = b1[c];
        #pragma unroll
        for (int k = 0; k < 64; ++k) acc += sp[g][k] * w1[k * 64 + c];
        sz[g][c] = fmaxf(acc, 0.f);
    }
    __syncthreads();
    if (t < 64) {
        float acc = b2[0];
        #pragma unroll
        for (int c = 0; c < 64; ++c) acc += sz[t][c] * w2[c];
        out[t] = 1.f / (1.f + __expf(-acc));
    }
}

extern "C" void kernel_launch(void* const* d_in, const int* in_sizes, int n_in,
                              void* d_out, int out_size, void* d_ws, size_t ws_size,
                              hipStream_t stream) {
    const float* x     = (const float*)d_in[0];
    const int*   ei    = (const int*)d_in[1];   // [2, NE] flat: src row then dst row
    const int*   batch = (const int*)d_in[2];
    const float* W     = (const float*)d_in[3];
    const float* att_s = (const float*)d_in[4];
    const float* att_d = (const float*)d_in[5];
    const float* bias  = (const float*)d_in[6];
    const float* w1    = (const float*)d_in[7];
    const float* b1    = (const float*)d_in[8];
    const float* w2    = (const float*)d_in[9];
    const float* b2    = (const float*)d_in[10];
    float* out = (float*)d_out;

    const int* src = ei;
    const int* dst = ei + NE;

    // workspace layout
    unsigned char* h8 = (unsigned char*)d_ws;        // NN*64 fp8 (3.2 MB)
    float* as_    = (float*)(h8 + (size_t)NN * HID); // NN
    float* ad_    = as_ + NN;                        // NN
    float* g      = ad_ + NN;                        // NN*64 f32 (12.8 MB, ebuf aliases)
    float* pooled = g + (size_t)NN * HID;            // NG*64
    float* cntp   = pooled + NG * HID;               // NG
    int*   deg    = (int*)(cntp + NG);               // NN
    int*   cursor = deg + NN;                        // NN
    int2*  csr2   = (int2*)(cursor + NN);            // NE int2 (6.4 MB)
    int*   gcur   = (int*)(csr2 + NE);               // NBUCK
    int2*  ebuf   = (int2*)g;                        // NBUCK*KC_CAP int2 (9.6 MB < 12.8)

    k_xw<<<(NN + 63) / 64, 256, 0, stream>>>(x, W, att_s, att_d, h8, as_, ad_, gcur);

    k_bucket<<<(NE + CHUNK - 1) / CHUNK, 256, 0, stream>>>(src, dst, as_, ad_, gcur, ebuf);
    k_csr<<<NBUCK, 256, 0, stream>>>(gcur, ebuf, csr2, cursor, deg);

    k_gather<<<(NN + 3) / 4, 256, 0, stream>>>(csr2, cursor, deg, h8, as_, ad_, bias, g, pooled);

    k_node<<<(NN / (4 * NPW)) + 1, 256, 0, stream>>>(g, batch, pooled, cntp);

    k_final<<<1, 256, 0, stream>>>(pooled, cntp, w1, b1, w2, b2, out);
}

// Round 18
// 141.317 us; speedup vs baseline: 3.1264x; 1.1038x over previous
//
#include <hip/hip_runtime.h>
#include <hip/hip_bf16.h>

#define NN 50000
#define NE 800000
#define NG 64
#define HID 64
#define NEG 0.2f
#define NPW 64          // nodes per wave in k_node
#define NBUCK 196       // ceil(NN/256) coarse buckets (dst>>8)
#define CHUNK 2048      // edges per k_bucket block
#define KC_CAP 6144     // per-bucket ebuf segment (mean 4081 + 32 sigma)

// ---- bf16 helpers ---------------------------------------------------------
__device__ __forceinline__ unsigned short f2bf(float f) {
    unsigned int u = __float_as_uint(f);
    unsigned int r = (u + 0x7FFF + ((u >> 16) & 1)) >> 16;   // RNE
    return (unsigned short)r;
}
__device__ __forceinline__ float bf2f(unsigned short b) {
    return __uint_as_float(((unsigned int)b) << 16);
}

// ---- fp8 e4m3 branch-free encode (RNE) / decode ---------------------------
__device__ __forceinline__ unsigned int f2fp8(float f) {
    unsigned int sign = (__float_as_uint(f) >> 24) & 0x80;
    float a = fminf(fabsf(f), 448.f);
    unsigned int au = __float_as_uint(a);
    unsigned int r = au + 0x7FFFF + ((au >> 20) & 1);        // RNE to 3 man bits
    unsigned int enc_n = (((r >> 23) - 120) << 3) | ((r >> 20) & 7);
    float t = fmaf(a, 512.f, 12582912.f);                    // 1.5*2^23 magic add
    unsigned int enc_d = (unsigned int)(__float_as_int(t) - 0x4B400000);
    unsigned int enc = (au < 0x3C800000u) ? enc_d : enc_n;
    return sign | enc;
}
__device__ __forceinline__ float fp8dec(int i) {             // LUT init only
    int e = (i >> 3) & 15, m = i & 7;
    float v = e ? ldexpf((float)(8 + m), e - 10) : ldexpf((float)m, -9);
    return (i & 0x80) ? -v : v;
}

// ---------------- K1: h(bf16) = x @ W ; a_s ; a_d --------------------------
// Exact r12 structure (known low-VGPR). Block 0 zeroes gcur.
__global__ __launch_bounds__(256)
void k_xw(const float* __restrict__ x, const float* __restrict__ W,
          const float* __restrict__ att_s, const float* __restrict__ att_d,
          unsigned short* __restrict__ hb, float* __restrict__ as_, float* __restrict__ ad_,
          int* __restrict__ gcur) {
    __shared__ __align__(16) float sW[64][64];    // [k][c]
    __shared__ __align__(16) float sxT[64][68];   // [k][r]
    int t = threadIdx.x;
    if (blockIdx.x == 0 && t < NBUCK) gcur[t] = 0;
    int r0 = blockIdx.x * 64;
    for (int i = t; i < 4096; i += 256) sW[i >> 6][i & 63] = W[i];
    for (int i = t; i < 4096; i += 256) {
        int r = i >> 6, c = i & 63;
        int gr = r0 + r; if (gr >= NN) gr = NN - 1;
        sxT[c][r] = x[(size_t)gr * 64 + c];
    }
    __syncthreads();

    int tx = t & 15, ty = t >> 4;
    float4 asv = ((const float4*)att_s)[tx];
    float4 adv = ((const float4*)att_d)[tx];

    float acc[4][4] = {};
    #pragma unroll
    for (int k = 0; k < 64; ++k) {
        float4 a = *(const float4*)&sxT[k][4 * ty];
        float4 b = *(const float4*)&sW[k][4 * tx];
        float av[4] = {a.x, a.y, a.z, a.w};
        float bv[4] = {b.x, b.y, b.z, b.w};
        #pragma unroll
        for (int i = 0; i < 4; ++i)
            #pragma unroll
            for (int j = 0; j < 4; ++j)
                acc[i][j] += av[i] * bv[j];
    }

    #pragma unroll
    for (int i = 0; i < 4; ++i) {
        int r = r0 + 4 * ty + i;
        if (r < NN) {
            ushort4 hv;
            hv.x = f2bf(acc[i][0]); hv.y = f2bf(acc[i][1]);
            hv.z = f2bf(acc[i][2]); hv.w = f2bf(acc[i][3]);
            *(ushort4*)&hb[(size_t)r * 64 + 4 * tx] = hv;     // 8B store
            float ps = acc[i][0]*asv.x + acc[i][1]*asv.y + acc[i][2]*asv.z + acc[i][3]*asv.w;
            float pd = acc[i][0]*adv.x + acc[i][1]*adv.y + acc[i][2]*adv.z + acc[i][3]*adv.w;
            #pragma unroll
            for (int m = 1; m <= 8; m <<= 1) {
                ps += __shfl_xor(ps, m, 64);
                pd += __shfl_xor(pd, m, 64);
            }
            if (tx == 0) { as_[r] = ps; ad_[r] = pd; }
        }
    }
}

// ---------------- K1b: bf16 -> fp8 streaming convert -----------------------
// Decoupled from the GEMM so its registers can't pressure the GEMM epilogue.
__global__ __launch_bounds__(256)
void k_enc(const unsigned short* __restrict__ hb, unsigned char* __restrict__ h8) {
    int i = blockIdx.x * 256 + threadIdx.x;       // one dword (4 elems) each
    if (i < NN * HID / 4) {
        ushort4 v = ((const ushort4*)hb)[i];
        unsigned int p = f2fp8(bf2f(v.x)) | (f2fp8(bf2f(v.y)) << 8)
                       | (f2fp8(bf2f(v.z)) << 16) | (f2fp8(bf2f(v.w)) << 24);
        ((unsigned int*)h8)[i] = p;
    }
}

// ---------------- Pass B: bucket sort + edge-weight precompute ------------
__global__ __launch_bounds__(256)
void k_bucket(const int* __restrict__ src, const int* __restrict__ dst,
              const float* __restrict__ as_, const float* __restrict__ ad_,
              int* __restrict__ gcur, int2* __restrict__ ebuf) {
    __shared__ int lhist[256], lscan[256], loff[256], lcur[256], gbase[256];
    __shared__ int2 lsort[CHUNK];
    __shared__ unsigned char lbuck[CHUNK];
    int t = threadIdx.x;
    int base = blockIdx.x * CHUNK;
    int cnt = NE - base; if (cnt > CHUNK) cnt = CHUNK; if (cnt < 0) cnt = 0;

    int ds[8], ss[8];
    float ex[8];
    int nv = 0;
    #pragma unroll
    for (int j = 0; j < 8; ++j) {
        int e = base + j * 256 + t;
        if (e < NE) { ds[nv] = dst[e]; ss[nv] = src[e]; ++nv; }
    }
    for (int j = 0; j < nv; ++j) {
        float e = as_[ss[j]] + ad_[ds[j]];
        e = e >= 0.f ? e : NEG * e;
        ex[j] = __expf(e);
    }
    lhist[t] = 0;
    __syncthreads();
    for (int j = 0; j < nv; ++j) atomicAdd(&lhist[ds[j] >> 8], 1);
    __syncthreads();
    lscan[t] = lhist[t];
    __syncthreads();
    for (int off = 1; off < 256; off <<= 1) {
        int u = (t >= off) ? lscan[t - off] : 0;
        __syncthreads();
        lscan[t] += u;
        __syncthreads();
    }
    loff[t] = lscan[t] - lhist[t];   // exclusive
    lcur[t] = 0;
    __syncthreads();
    for (int j = 0; j < nv; ++j) {
        int b = ds[j] >> 8;
        int r = atomicAdd(&lcur[b], 1);
        int slot = loff[b] + r;
        lsort[slot] = make_int2((ss[j] << 8) | (ds[j] & 255), __float_as_int(ex[j]));
        lbuck[slot] = (unsigned char)b;
    }
    if (t < NBUCK) {
        int c = lhist[t];
        gbase[t] = c ? atomicAdd(&gcur[t], c) : 0;    // offset WITHIN bucket t
    }
    __syncthreads();
    for (int i = t; i < cnt; i += 256) {
        int b = lbuck[i];
        ebuf[b * KC_CAP + gbase[b] + (i - loff[b])] = lsort[i];
    }
}

// ---------------- Pass C: exact CSR within each bucket --------------------
__global__ __launch_bounds__(256)
void k_csr(const int* __restrict__ gcur, const int2* __restrict__ ebuf,
           int2* __restrict__ csr2, int* __restrict__ cursor, int* __restrict__ deg) {
    __shared__ int lhist[256], lscan[256], loff[256], lcur[256], bscan[256];
    __shared__ int2 lsrc[KC_CAP];
    int t = threadIdx.x;
    int b = blockIdx.x;

    bscan[t] = (t < NBUCK) ? gcur[t] : 0;
    __syncthreads();
    for (int off = 1; off < 256; off <<= 1) {
        int u = (t >= off) ? bscan[t - off] : 0;
        __syncthreads();
        bscan[t] += u;
        __syncthreads();
    }
    int sz = gcur[b];
    int gb = bscan[b] - sz;
    const int2* seg = ebuf + b * KC_CAP;

    lhist[t] = 0;
    __syncthreads();
    for (int i = t; i < sz; i += 256)
        atomicAdd(&lhist[seg[i].x & 255], 1);
    __syncthreads();
    lscan[t] = lhist[t];
    __syncthreads();
    for (int off = 1; off < 256; off <<= 1) {
        int u = (t >= off) ? lscan[t - off] : 0;
        __syncthreads();
        lscan[t] += u;
        __syncthreads();
    }
    loff[t] = lscan[t] - lhist[t];
    lcur[t] = 0;
    __syncthreads();
    for (int i = t; i < sz; i += 256) {
        int2 w = seg[i];
        int dl = w.x & 255;
        int r = atomicAdd(&lcur[dl], 1);
        lsrc[loff[dl] + r] = make_int2(w.x >> 8, w.y);
    }
    __syncthreads();
    for (int i = t; i < sz; i += 256)
        csr2[gb + i] = lsrc[i];
    int d = b * 256 + t;
    if (d < NN) {
        deg[d] = lhist[t];
        cursor[d] = gb + loff[t] + lhist[t];   // end offset
    }
}

// ---------------- K2': gather, 8 edges/iter, fp8 h + LDS LUT decode -------
__global__ __launch_bounds__(256)
void k_gather(const int2* __restrict__ csr2, const int* __restrict__ cursor,
              const int* __restrict__ deg, const unsigned char* __restrict__ h8,
              const float* __restrict__ as_, const float* __restrict__ ad_,
              const float* __restrict__ bias, float* __restrict__ g,
              float* __restrict__ poolz) {
    __shared__ float lut[256];
    int t = threadIdx.x;
    if (t < 256) lut[t] = fp8dec(t);
    if (blockIdx.x == 0) {
        for (int i = t; i < NG * HID + NG; i += 256) poolz[i] = 0.f;
    }
    __syncthreads();
    int wave = t >> 6, lane = t & 63;
    int d = blockIdx.x * 4 + wave;
    if (d >= NN) return;
    int grp = lane >> 3;          // edge group 0..7
    int cc  = lane & 7;           // channel slice (8 channels each)
    int cend = cursor[d];
    int nd   = deg[d];
    int cbeg = cend - nd;

    float acc[8] = {};
    float den = 0.f;

    // self-loop (weight nonzero only in group 0; summed once by the reduce)
    {
        float e0 = as_[d] + ad_[d];
        e0 = e0 >= 0.f ? e0 : NEG * e0;
        float ex0 = (grp == 0) ? __expf(e0) : 0.f;
        den += ex0;
        uint2 v = *(const uint2*)&h8[(size_t)d * 64 + 8 * cc];
        acc[0] += lut[v.x & 255] * ex0;         acc[1] += lut[(v.x >> 8) & 255] * ex0;
        acc[2] += lut[(v.x >> 16) & 255] * ex0; acc[3] += lut[(v.x >> 24) & 255] * ex0;
        acc[4] += lut[v.y & 255] * ex0;         acc[5] += lut[(v.y >> 8) & 255] * ex0;
        acc[6] += lut[(v.y >> 16) & 255] * ex0; acc[7] += lut[(v.y >> 24) & 255] * ex0;
    }

    for (int c0 = 0; c0 < nd; c0 += 8) {
        int  e  = c0 + grp;
        bool ok = e < nd;
        int  ci = cbeg + (ok ? e : (nd - 1));
        int2 se = csr2[ci];                       // coalesced (s, ex)
        int    s  = se.x;
        float  ex = ok ? __int_as_float(se.y) : 0.f;
        den += ex;
        uint2 v = *(const uint2*)&h8[(size_t)s * 64 + 8 * cc];   // 8B/lane, 64B row
        acc[0] += lut[v.x & 255] * ex;         acc[1] += lut[(v.x >> 8) & 255] * ex;
        acc[2] += lut[(v.x >> 16) & 255] * ex; acc[3] += lut[(v.x >> 24) & 255] * ex;
        acc[4] += lut[v.y & 255] * ex;         acc[5] += lut[(v.y >> 8) & 255] * ex;
        acc[6] += lut[(v.y >> 16) & 255] * ex; acc[7] += lut[(v.y >> 24) & 255] * ex;
    }

    #pragma unroll
    for (int m = 8; m <= 32; m <<= 1) {
        den += __shfl_xor(den, m, 64);
        #pragma unroll
        for (int k = 0; k < 8; ++k) acc[k] += __shfl_xor(acc[k], m, 64);
    }

    if (grp == 0) {                               // 8 lanes write the row
        float inv = 1.f / den;
        float4 b0 = ((const float4*)bias)[2 * cc];
        float4 b1 = ((const float4*)bias)[2 * cc + 1];
        float4 o0, o1;
        o0.x = fmaxf(acc[0] * inv + b0.x, 0.f);
        o0.y = fmaxf(acc[1] * inv + b0.y, 0.f);
        o0.z = fmaxf(acc[2] * inv + b0.z, 0.f);
        o0.w = fmaxf(acc[3] * inv + b0.w, 0.f);
        o1.x = fmaxf(acc[4] * inv + b1.x, 0.f);
        o1.y = fmaxf(acc[5] * inv + b1.y, 0.f);
        o1.z = fmaxf(acc[6] * inv + b1.z, 0.f);
        o1.w = fmaxf(acc[7] * inv + b1.w, 0.f);
        *(float4*)&g[(size_t)d * 64 + 8 * cc]     = o0;
        *(float4*)&g[(size_t)d * 64 + 8 * cc + 4] = o1;
    }
}

// ---------------- K3: pooled partial sums (batch sorted, run-length) ------
__global__ __launch_bounds__(256)
void k_node(const float* __restrict__ g, const int* __restrict__ batch,
            float* __restrict__ pooled, float* __restrict__ cnt) {
    int t = threadIdx.x;
    int wave = t >> 6, lane = t & 63;
    int n0 = (blockIdx.x * 4 + wave) * NPW;
    if (n0 >= NN) return;
    int n1 = n0 + NPW; if (n1 > NN) n1 = NN;
    float acc = 0.f, c = 0.f;
    int cur = batch[n0];
    for (int n = n0; n < n1; ++n) {
        int gr = batch[n];
        if (gr != cur) {
            atomicAdd(&pooled[cur * 64 + lane], acc);
            if (lane == 0) atomicAdd(&cnt[cur], c);
            acc = 0.f; c = 0.f; cur = gr;
        }
        acc += g[(size_t)n * 64 + lane];
        c += 1.f;
    }
    atomicAdd(&pooled[cur * 64 + lane], acc);
    if (lane == 0) atomicAdd(&cnt[cur], c);
}

// ---------------- K4: mean + MLP + sigmoid (single block) ------------------
__global__ __launch_bounds__(256)
void k_final(const float* __restrict__ pooled, const float* __restrict__ cnt,
             const float* __restrict__ w1, const float* __restrict__ b1,
             const float* __restrict__ w2, const float* __restrict__ b2,
             float* __restrict__ out) {
    __shared__ float sp[64][65];
    __shared__ float sz[64][65];
    int t = threadIdx.x;
    for (int i = t; i < 4096; i += 256) {
        int g = i >> 6, c = i & 63;
        sp[g][c] = pooled[i] / fmaxf(cnt[g], 1.0f);
    }
    __syncthreads();
    for (int i = t; i < 4096; i += 256) {
        int g = i >> 6, c = i & 63;
        float acc = b1[c];
        #pragma unroll
        for (int k = 0; k < 64; ++k) acc += sp[g][k] * w1[k * 64 + c];
        sz[g][c] = fmaxf(acc, 0.f);
    }
    __syncthreads();
    if (t < 64) {
        float acc = b2[0];
        #pragma unroll
        for (int c = 0; c < 64; ++c) acc += sz[t][c] * w2[c];
        out[t] = 1.f / (1.f + __expf(-acc));
    }
}

extern "C" void kernel_launch(void* const* d_in, const int* in_sizes, int n_in,
                              void* d_out, int out_size, void* d_ws, size_t ws_size,
                              hipStream_t stream) {
    const float* x     = (const float*)d_in[0];
    const int*   ei    = (const int*)d_in[1];   // [2, NE] flat: src row then dst row
    const int*   batch = (const int*)d_in[2];
    const float* W     = (const float*)d_in[3];
    const float* att_s = (const float*)d_in[4];
    const float* att_d = (const float*)d_in[5];
    const float* bias  = (const float*)d_in[6];
    const float* w1    = (const float*)d_in[7];
    const float* b1    = (const float*)d_in[8];
    const float* w2    = (const float*)d_in[9];
    const float* b2    = (const float*)d_in[10];
    float* out = (float*)d_out;

    const int* src = ei;
    const int* dst = ei + NE;

    // workspace layout
    unsigned char* h8 = (unsigned char*)d_ws;        // NN*64 fp8  (3.2 MB)
    unsigned short* hb = (unsigned short*)(h8 + (size_t)NN * HID);  // NN*64 bf16 (6.4 MB)
    float* as_    = (float*)(hb + (size_t)NN * HID); // NN
    float* ad_    = as_ + NN;                        // NN
    float* g      = ad_ + NN;                        // NN*64 f32 (12.8 MB, ebuf aliases)
    float* pooled = g + (size_t)NN * HID;            // NG*64
    float* cntp   = pooled + NG * HID;               // NG
    int*   deg    = (int*)(cntp + NG);               // NN
    int*   cursor = deg + NN;                        // NN
    int2*  csr2   = (int2*)(cursor + NN);            // NE int2 (6.4 MB)
    int*   gcur   = (int*)(csr2 + NE);               // NBUCK
    int2*  ebuf   = (int2*)g;                        // NBUCK*KC_CAP int2 (9.6 MB < 12.8)

    k_xw<<<(NN + 63) / 64, 256, 0, stream>>>(x, W, att_s, att_d, hb, as_, ad_, gcur);

    k_enc<<<(NN * HID / 4 + 255) / 256, 256, 0, stream>>>(hb, h8);

    k_bucket<<<(NE + CHUNK - 1) / CHUNK, 256, 0, stream>>>(src, dst, as_, ad_, gcur, ebuf);
    k_csr<<<NBUCK, 256, 0, stream>>>(gcur, ebuf, csr2, cursor, deg);

    k_gather<<<(NN + 3) / 4, 256, 0, stream>>>(csr2, cursor, deg, h8, as_, ad_, bias, g, pooled);

    k_node<<<(NN / (4 * NPW)) + 1, 256, 0, stream>>>(g, batch, pooled, cntp);

    k_final<<<1, 256, 0, stream>>>(pooled, cntp, w1, b1, w2, b2, out);
}